// Round 21
// baseline (119.330 us; speedup 1.0000x reference)
//
#include <hip/hip_runtime.h>
#include <hip/hip_bf16.h>

typedef __attribute__((ext_vector_type(8))) short bf16x8;
typedef __attribute__((ext_vector_type(4))) short bf16x4;
typedef __attribute__((ext_vector_type(4))) float f32x4;

static __device__ __forceinline__ __hip_bfloat16 f2b(float f) {
    return __float2bfloat16(f);
}
static __device__ __forceinline__ unsigned pack2(float a, float b) {
    unsigned ua = (unsigned)__bfloat16_as_ushort(__float2bfloat16(a));
    unsigned ub = (unsigned)__bfloat16_as_ushort(__float2bfloat16(b));
    return ua | (ub << 16);
}
static __device__ __forceinline__ float exp2fast(float x) {
    return __builtin_amdgcn_exp2f(x);
}
static __device__ __forceinline__ float b2f(short u) {
    unsigned ub = ((unsigned)(unsigned short)u) << 16;
    float f;
    __builtin_memcpy(&f, &ub, 4);
    return f;
}

#define QSCALE 0.1803368801111f   // 0.125 * log2(e)

// ---------------------------------------------------------------------------
// Fused prep: blocks [0,2048) convert x f32->bf16; [2048,5120) transpose
// Wqkv -> WqkvT bf16; [5120,6144) transpose Wo -> WoT bf16.
// ---------------------------------------------------------------------------
__global__ __launch_bounds__(256) void k_prep(
    const float* __restrict__ x, __hip_bfloat16* __restrict__ xb,
    const float* __restrict__ Wqkv, __hip_bfloat16* __restrict__ WqkvT,
    const float* __restrict__ Wo, __hip_bfloat16* __restrict__ WoT)
{
    const int bx = blockIdx.x;
    if (bx < 2048) {
        int i = bx * 256 + threadIdx.x;
        const int stride = 2048 * 256;
        for (; i < 1048576; i += stride) {
            float4 v = reinterpret_cast<const float4*>(x)[i];
            __hip_bfloat16* o = xb + 4 * (size_t)i;
            o[0] = f2b(v.x); o[1] = f2b(v.y); o[2] = f2b(v.z); o[3] = f2b(v.w);
        }
        return;
    }
    __shared__ float tile[32][33];
    const float* in;
    __hip_bfloat16* outp;
    int R, Cn, c0, r0;
    if (bx < 5120) {
        const int b = bx - 2048;
        in = Wqkv; outp = WqkvT; R = 1024; Cn = 3072;
        c0 = (b % 96) * 32; r0 = (b / 96) * 32;
    } else {
        const int b = bx - 5120;
        in = Wo; outp = WoT; R = 1024; Cn = 1024;
        c0 = (b & 31) * 32; r0 = (b >> 5) * 32;
    }
    const int tx = threadIdx.x & 31, ty = threadIdx.x >> 5;
#pragma unroll
    for (int i = 0; i < 32; i += 8)
        tile[ty + i][tx] = in[(size_t)(r0 + ty + i) * Cn + c0 + tx];
    __syncthreads();
#pragma unroll
    for (int i = 0; i < 32; i += 8)
        outp[(size_t)(c0 + ty + i) * R + r0 + tx] = f2b(tile[tx][ty + i]);
}

// ---------------------------------------------------------------------------
// GEMM1 qkv: 128x128 tile, BK=32, THREE-buffer LDS, counted-vmcnt pipeline.
// (round-13 version, verified)
// ---------------------------------------------------------------------------
#define QK_STAGE(buf, kt)                                                       \
    {                                                                           \
        const int k0_ = (kt) << 5;                                              \
        _Pragma("unroll")                                                       \
        for (int i = 0; i < 2; ++i) {                                           \
            const int idx = i * 256 + tid;                                      \
            const int r_ = idx >> 2;                                            \
            const int j_ = idx & 3;                                             \
            const int js_ = j_ ^ ((r_ >> 1) & 3);                               \
            __builtin_amdgcn_global_load_lds(                                   \
                (const __attribute__((address_space(1))) void*)(A + (size_t)(m0 + r_) * K + k0_ + js_ * 8), \
                (__attribute__((address_space(3))) void*)(&As[buf][r_][j_ * 8]), 16, 0, 0); \
        }                                                                       \
        _Pragma("unroll")                                                       \
        for (int i = 0; i < 2; ++i) {                                           \
            const int idx = i * 256 + tid;                                      \
            const int r_ = idx >> 2;                                            \
            const int j_ = idx & 3;                                             \
            const int js_ = j_ ^ ((r_ >> 1) & 3);                               \
            __builtin_amdgcn_global_load_lds(                                   \
                (const __attribute__((address_space(1))) void*)(Bt + (size_t)(n0 + r_) * K + k0_ + js_ * 8), \
                (__attribute__((address_space(3))) void*)(&Bs[buf][r_][j_ * 8]), 16, 0, 0); \
        }                                                                       \
    }

__global__ __launch_bounds__(256, 3) void k_gemm_qkv(
    const __hip_bfloat16* __restrict__ A,
    const __hip_bfloat16* __restrict__ Bt,
    const float* __restrict__ bias,
    int K,
    __hip_bfloat16* __restrict__ Qb,
    __hip_bfloat16* __restrict__ Kb,
    __hip_bfloat16* __restrict__ Vt)
{
    __shared__ __hip_bfloat16 As[3][128][32];
    __shared__ __hip_bfloat16 Bs[3][128][32];

    const int tid = threadIdx.x;
    const int lane = tid & 63;
    const int wid = tid >> 6;
    const int wm = wid >> 1, wn = wid & 1;
    const int m0 = blockIdx.y * 128, n0 = blockIdx.x * 128;
    const int l15 = lane & 15, lg = lane >> 4;
    const int rchunk = (lg ^ ((l15 >> 1) & 3)) * 8;

    f32x4 acc[4][4] = {};
    const int nt = K >> 5;   // 32

    QK_STAGE(0, 0);
    QK_STAGE(1, 1);
    asm volatile("s_waitcnt vmcnt(4)" ::: "memory");
    __builtin_amdgcn_sched_barrier(0);
    __builtin_amdgcn_s_barrier();
    __builtin_amdgcn_sched_barrier(0);

    for (int t = 0; t < nt; ++t) {
        const int cur = t % 3;
        if (t + 2 < nt) {
            const int nxt = (t + 2) % 3;
            QK_STAGE(nxt, t + 2);
        }
        bf16x8 a[4], bb[4];
#pragma unroll
        for (int m = 0; m < 4; ++m)
            a[m] = *(const bf16x8*)&As[cur][wm * 64 + m * 16 + l15][rchunk];
#pragma unroll
        for (int n = 0; n < 4; ++n)
            bb[n] = *(const bf16x8*)&Bs[cur][wn * 64 + n * 16 + l15][rchunk];
        __builtin_amdgcn_s_setprio(1);
#pragma unroll
        for (int m = 0; m < 4; ++m)
#pragma unroll
            for (int n = 0; n < 4; ++n)
                acc[m][n] = __builtin_amdgcn_mfma_f32_16x16x32_bf16(a[m], bb[n], acc[m][n], 0, 0, 0);
        __builtin_amdgcn_s_setprio(0);
        __builtin_amdgcn_sched_barrier(0);
        if (t + 2 < nt)
            asm volatile("s_waitcnt vmcnt(4)" ::: "memory");
        else
            asm volatile("s_waitcnt vmcnt(0)" ::: "memory");
        __builtin_amdgcn_sched_barrier(0);
        __builtin_amdgcn_s_barrier();
        __builtin_amdgcn_sched_barrier(0);
    }

#pragma unroll
    for (int m = 0; m < 4; ++m) {
        const int row = m0 + wm * 64 + m * 16 + lg * 4;
#pragma unroll
        for (int n = 0; n < 4; ++n) {
            const int col = n0 + wn * 64 + n * 16 + l15;
            const float bv = bias[col];
#pragma unroll
            for (int r = 0; r < 4; ++r) {
                const float val = acc[m][n][r] + bv;
                const int rr = row + r;
                const int sec = col >> 10, cw = col & 1023;
                const int hh = cw >> 6, d = cw & 63;
                const int bq = rr >> 11, tt = rr & 2047;
                const int bh = bq * 16 + hh;
                if (sec == 0)
                    Qb[((size_t)bh * 2048 + tt) * 64 + d] = f2b(val * QSCALE);
                else if (sec == 1)
                    Kb[((size_t)bh * 2048 + tt) * 64 + d] = f2b(val);
                else
                    Vt[((size_t)bh * 64 + d) * 2048 + tt] = f2b(val);
            }
        }
    }
}

// ---------------------------------------------------------------------------
// GEMM out: 128x64 tile, BK=32, THREE-buffer counted-vmcnt pipeline.
// (round-15 version, verified)
// ---------------------------------------------------------------------------
#define OUT_STAGE(buf, kt)                                                      \
    {                                                                           \
        const int k0_ = (kt) << 5;                                              \
        _Pragma("unroll")                                                       \
        for (int i = 0; i < 2; ++i) {                                           \
            const int idx = i * 256 + tid;                                      \
            const int r_ = idx >> 2;                                            \
            const int j_ = idx & 3;                                             \
            const int js_ = j_ ^ ((r_ >> 1) & 3);                               \
            __builtin_amdgcn_global_load_lds(                                   \
                (const __attribute__((address_space(1))) void*)(A + (size_t)(m0 + r_) * K + k0_ + js_ * 8), \
                (__attribute__((address_space(3))) void*)(&As[buf][r_][j_ * 8]), 16, 0, 0); \
        }                                                                       \
        {                                                                       \
            const int r_ = tid >> 2;                                            \
            const int j_ = tid & 3;                                             \
            const int js_ = j_ ^ ((r_ >> 1) & 3);                               \
            __builtin_amdgcn_global_load_lds(                                   \
                (const __attribute__((address_space(1))) void*)(Bt + (size_t)(n0 + r_) * K + k0_ + js_ * 8), \
                (__attribute__((address_space(3))) void*)(&Bs[buf][r_][j_ * 8]), 16, 0, 0); \
        }                                                                       \
    }

__global__ __launch_bounds__(256, 4) void k_gemm_out(
    const __hip_bfloat16* __restrict__ A,
    const __hip_bfloat16* __restrict__ Bt,
    const float* __restrict__ bias,
    int K, int Nn,
    float* __restrict__ outf)
{
    __shared__ __hip_bfloat16 As[3][128][32];
    __shared__ __hip_bfloat16 Bs[3][64][32];

    const int tid = threadIdx.x;
    const int lane = tid & 63;
    const int wid = tid >> 6;
    const int wm = wid >> 1, wn = wid & 1;
    const int m0 = blockIdx.y * 128, n0 = blockIdx.x * 64;
    const int l15 = lane & 15, lg = lane >> 4;
    const int rchunk = (lg ^ ((l15 >> 1) & 3)) * 8;

    f32x4 acc[4][2] = {};
    const int nt = K >> 5;   // 32

    OUT_STAGE(0, 0);
    OUT_STAGE(1, 1);
    asm volatile("s_waitcnt vmcnt(3)" ::: "memory");
    __builtin_amdgcn_sched_barrier(0);
    __builtin_amdgcn_s_barrier();
    __builtin_amdgcn_sched_barrier(0);

    for (int t = 0; t < nt; ++t) {
        const int cur = t % 3;
        if (t + 2 < nt) {
            const int nxt = (t + 2) % 3;
            OUT_STAGE(nxt, t + 2);
        }
        bf16x8 a[4], bb[2];
#pragma unroll
        for (int m = 0; m < 4; ++m)
            a[m] = *(const bf16x8*)&As[cur][wm * 64 + m * 16 + l15][rchunk];
#pragma unroll
        for (int n = 0; n < 2; ++n)
            bb[n] = *(const bf16x8*)&Bs[cur][wn * 32 + n * 16 + l15][rchunk];
        __builtin_amdgcn_s_setprio(1);
#pragma unroll
        for (int m = 0; m < 4; ++m)
#pragma unroll
            for (int n = 0; n < 2; ++n)
                acc[m][n] = __builtin_amdgcn_mfma_f32_16x16x32_bf16(a[m], bb[n], acc[m][n], 0, 0, 0);
        __builtin_amdgcn_s_setprio(0);
        __builtin_amdgcn_sched_barrier(0);
        if (t + 2 < nt)
            asm volatile("s_waitcnt vmcnt(3)" ::: "memory");
        else
            asm volatile("s_waitcnt vmcnt(0)" ::: "memory");
        __builtin_amdgcn_sched_barrier(0);
        __builtin_amdgcn_s_barrier();
        __builtin_amdgcn_sched_barrier(0);
    }

#pragma unroll
    for (int m = 0; m < 4; ++m) {
        const int row = m0 + wm * 64 + m * 16 + lg * 4;
#pragma unroll
        for (int n = 0; n < 2; ++n) {
            const int col = n0 + wn * 32 + n * 16 + l15;
            const float bv = bias[col];
#pragma unroll
            for (int r = 0; r < 4; ++r)
                outf[(size_t)(row + r) * Nn + col] = acc[m][n][r] + bv;
        }
    }
}

// ---------------------------------------------------------------------------
// Causal flash attention v16 — round-20 high-occupancy staged kernel
// (16 q-rows/wave, 1024-block-equivalent math, VGPR 56, verified 45.9 us)
// + CROSS-BLOCK SPLIT-K: each (head, 64-row q-tile) splits its key range
// into two halves -> 2048 blocks, critical path 32 -> ~17 steps.
// half0: full steps [0, nA); half1: [nA, tile) + masked tail.
// Partials: half0 -> att (unnormalized) + Pml[0]; half1 -> Po + Pml[1];
// k_attn_merge combines (round-12 machinery, numerically verified).
// Work-descending dispatch: u=0 -> tile31/half1 (17 steps) first.
// ---------------------------------------------------------------------------
#define DEFER_THR 4.0f

#define AT_STAGE(buf, tt)                                                       \
    {                                                                           \
        const int ks_ = (tt) << 6;                                              \
        _Pragma("unroll")                                                       \
        for (int i = 0; i < 2; ++i) {                                           \
            const int idx = i * 256 + tid;                                      \
            const int r_ = idx >> 3;                                            \
            const int j_ = idx & 7;                                             \
            const int js_ = j_ ^ (r_ & 7);                                      \
            __builtin_amdgcn_global_load_lds(                                   \
                (const __attribute__((address_space(1))) void*)(Kbase + (size_t)(ks_ + r_) * 64 + js_ * 8), \
                (__attribute__((address_space(3))) void*)(&Ks[buf][r_][j_ * 8]), 16, 0, 0); \
        }                                                                       \
        _Pragma("unroll")                                                       \
        for (int i = 0; i < 2; ++i) {                                           \
            const int idx = i * 256 + tid;                                      \
            const int r_ = idx >> 3;                                            \
            const int j_ = idx & 7;                                             \
            const int js_ = j_ ^ (r_ & 7);                                      \
            __builtin_amdgcn_global_load_lds(                                   \
                (const __attribute__((address_space(1))) void*)(Vbase + (size_t)r_ * 2048 + ks_ + js_ * 8), \
                (__attribute__((address_space(3))) void*)(&Vs[buf][r_][j_ * 8]), 16, 0, 0); \
        }                                                                       \
    }

#define FULL_STEP_L(BUF)                                                        \
    {                                                                           \
        bf16x8 bk0[4], bk1[4];                                                  \
        _Pragma("unroll")                                                       \
        for (int kf = 0; kf < 4; ++kf) {                                        \
            bk0[kf] = *(const bf16x8*)&Ks[BUF][kf * 16 + l15][(lg ^ kswz) * 8]; \
            bk1[kf] = *(const bf16x8*)&Ks[BUF][kf * 16 + l15][((4 + lg) ^ kswz) * 8]; \
        }                                                                       \
        f32x4 s[4] = {};                                                        \
        __builtin_amdgcn_s_setprio(1);                                          \
        _Pragma("unroll")                                                       \
        for (int kf = 0; kf < 4; ++kf) {                                        \
            s[kf] = __builtin_amdgcn_mfma_f32_16x16x32_bf16(bk0[kf], aq0, s[kf], 0, 0, 0); \
            s[kf] = __builtin_amdgcn_mfma_f32_16x16x32_bf16(bk1[kf], aq1, s[kf], 0, 0, 0); \
        }                                                                       \
        __builtin_amdgcn_s_setprio(0);                                          \
        float px = fmaxf(fmaxf(fmaxf(s[0][0], s[0][1]), fmaxf(s[0][2], s[0][3])), \
                         fmaxf(fmaxf(s[1][0], s[1][1]), fmaxf(s[1][2], s[1][3]))); \
        px = fmaxf(px, fmaxf(fmaxf(fmaxf(s[2][0], s[2][1]), fmaxf(s[2][2], s[2][3])), \
                             fmaxf(fmaxf(s[3][0], s[3][1]), fmaxf(s[3][2], s[3][3])))); \
        px = fmaxf(px, __shfl_xor(px, 16));                                     \
        px = fmaxf(px, __shfl_xor(px, 32));                                     \
        if (__any(px > m0 + DEFER_THR)) {                                       \
            const float mn_ = fmaxf(m0, px);                                    \
            const float al_ = exp2fast(m0 - mn_);                               \
            m0 = mn_; l0 *= al_;                                                \
            _Pragma("unroll")                                                   \
            for (int dc = 0; dc < 4; ++dc)                                      \
                _Pragma("unroll")                                               \
                for (int r = 0; r < 4; ++r) o[dc][r] *= al_;                    \
        }                                                                       \
        float rs_ = 0.f;                                                        \
        _Pragma("unroll")                                                       \
        for (int kf = 0; kf < 4; ++kf) {                                        \
            _Pragma("unroll")                                                   \
            for (int r = 0; r < 4; ++r) {                                       \
                s[kf][r] = exp2fast(s[kf][r] - m0);                             \
                rs_ += s[kf][r];                                                \
            }                                                                   \
            uint2 w_;                                                           \
            w_.x = pack2(s[kf][0], s[kf][1]);                                   \
            w_.y = pack2(s[kf][2], s[kf][3]);                                   \
            *(uint2*)&Pw[l15 * 64 + ((kf * 16 + lg * 4) ^ swz)] = w_;           \
        }                                                                       \
        rs_ += __shfl_xor(rs_, 16);                                             \
        rs_ += __shfl_xor(rs_, 32);                                             \
        l0 += rs_;                                                              \
        _Pragma("unroll")                                                       \
        for (int c2 = 0; c2 < 2; ++c2) {                                        \
            bf16x8 bv[4];                                                       \
            _Pragma("unroll")                                                   \
            for (int dc = 0; dc < 4; ++dc)                                      \
                bv[dc] = *(const bf16x8*)&Vs[BUF][dc * 16 + l15][(((c2 << 2) | lg) ^ kswz) * 8]; \
            const bf16x8 pb = *(const bf16x8*)&Pw[l15 * 64 + ((c2 * 32 + lg * 8) ^ swz)]; \
            __builtin_amdgcn_s_setprio(1);                                      \
            _Pragma("unroll")                                                   \
            for (int dc = 0; dc < 4; ++dc)                                      \
                o[dc] = __builtin_amdgcn_mfma_f32_16x16x32_bf16(bv[dc], pb, o[dc], 0, 0, 0); \
            __builtin_amdgcn_s_setprio(0);                                      \
        }                                                                       \
    }

#define TAIL_STEP_L(BUF)                                                        \
    {                                                                           \
        const int ks_ = nfull * 64;                                             \
        const int qv = qw + l15;                                                \
        bf16x8 bk0[4], bk1[4];                                                  \
        _Pragma("unroll")                                                       \
        for (int kf = 0; kf < 4; ++kf) {                                        \
            bk0[kf] = *(const bf16x8*)&Ks[BUF][kf * 16 + l15][(lg ^ kswz) * 8]; \
            bk1[kf] = *(const bf16x8*)&Ks[BUF][kf * 16 + l15][((4 + lg) ^ kswz) * 8]; \
        }                                                                       \
        f32x4 s[4] = {};                                                        \
        _Pragma("unroll")                                                       \
        for (int kf = 0; kf < 4; ++kf) {                                        \
            if (ks_ + kf * 16 <= qw + 15) {                                     \
                s[kf] = __builtin_amdgcn_mfma_f32_16x16x32_bf16(bk0[kf], aq0, s[kf], 0, 0, 0); \
                s[kf] = __builtin_amdgcn_mfma_f32_16x16x32_bf16(bk1[kf], aq1, s[kf], 0, 0, 0); \
            }                                                                   \
        }                                                                       \
        const int kb = ks_ + lg * 4;                                            \
        _Pragma("unroll")                                                       \
        for (int kf = 0; kf < 4; ++kf)                                          \
            _Pragma("unroll")                                                   \
            for (int r = 0; r < 4; ++r)                                         \
                s[kf][r] = (kb + kf * 16 + r <= qv) ? s[kf][r] : -1e30f;        \
        float mx = fmaxf(fmaxf(fmaxf(s[0][0], s[0][1]), fmaxf(s[0][2], s[0][3])), \
                         fmaxf(fmaxf(s[1][0], s[1][1]), fmaxf(s[1][2], s[1][3]))); \
        mx = fmaxf(mx, fmaxf(fmaxf(fmaxf(s[2][0], s[2][1]), fmaxf(s[2][2], s[2][3])), \
                             fmaxf(fmaxf(s[3][0], s[3][1]), fmaxf(s[3][2], s[3][3])))); \
        mx = fmaxf(mx, __shfl_xor(mx, 16));                                     \
        mx = fmaxf(mx, __shfl_xor(mx, 32));                                     \
        const float mnew = fmaxf(m0, mx);                                       \
        const float al_ = exp2fast(m0 - mnew);                                  \
        m0 = mnew;                                                              \
        float rs_ = 0.f;                                                        \
        _Pragma("unroll")                                                       \
        for (int kf = 0; kf < 4; ++kf)                                          \
            _Pragma("unroll")                                                   \
            for (int r = 0; r < 4; ++r) {                                       \
                s[kf][r] = exp2fast(s[kf][r] - mnew);                           \
                rs_ += s[kf][r];                                                \
            }                                                                   \
        rs_ += __shfl_xor(rs_, 16);                                             \
        rs_ += __shfl_xor(rs_, 32);                                             \
        l0 = l0 * al_ + rs_;                                                    \
        _Pragma("unroll")                                                       \
        for (int dc = 0; dc < 4; ++dc)                                          \
            _Pragma("unroll")                                                   \
            for (int r = 0; r < 4; ++r) o[dc][r] *= al_;                        \
        _Pragma("unroll")                                                       \
        for (int kf = 0; kf < 4; ++kf) {                                        \
            uint2 w_;                                                           \
            w_.x = pack2(s[kf][0], s[kf][1]);                                   \
            w_.y = pack2(s[kf][2], s[kf][3]);                                   \
            *(uint2*)&Pw[l15 * 64 + ((kf * 16 + lg * 4) ^ swz)] = w_;           \
        }                                                                       \
        _Pragma("unroll")                                                       \
        for (int c2 = 0; c2 < 2; ++c2) {                                        \
            if (ks_ + c2 * 32 <= qw + 15) {                                     \
                bf16x8 bv[4];                                                   \
                _Pragma("unroll")                                               \
                for (int dc = 0; dc < 4; ++dc)                                  \
                    bv[dc] = *(const bf16x8*)&Vs[BUF][dc * 16 + l15][(((c2 << 2) | lg) ^ kswz) * 8]; \
                const bf16x8 pb = *(const bf16x8*)&Pw[l15 * 64 + ((c2 * 32 + lg * 8) ^ swz)]; \
                _Pragma("unroll")                                               \
                for (int dc = 0; dc < 4; ++dc)                                  \
                    o[dc] = __builtin_amdgcn_mfma_f32_16x16x32_bf16(bv[dc], pb, o[dc], 0, 0, 0); \
            }                                                                   \
        }                                                                       \
    }

__global__ __launch_bounds__(256, 4) void k_attn(
    const __hip_bfloat16* __restrict__ Qb,
    const __hip_bfloat16* __restrict__ Kb,
    const __hip_bfloat16* __restrict__ Vt,
    __hip_bfloat16* __restrict__ att,     // half-0 partial O (un-normalized)
    __hip_bfloat16* __restrict__ Po,      // half-1 partial O
    float* __restrict__ Pml)              // [2][65536] float2 (m,l)
{
    __shared__ __hip_bfloat16 Ks[2][64][64];          // 16 KB
    __shared__ __hip_bfloat16 Vs[2][64][64];          // 16 KB (row=d, col=key)
    __shared__ __hip_bfloat16 P_lds[4][16 * 64];      //  8 KB
    const int tid = threadIdx.x, lane = tid & 63, wid = tid >> 6;
    const int lid = blockIdx.x;                  // 0..2047
    const int xcd = lid & 7, j = lid >> 3;       // j 0..255
    const int bh = xcd * 4 + (j & 3);            // 4 heads per XCD
    const int u = j >> 2;                        // 0..63
    const int tile = 31 - (u >> 1);              // heavy tiles first
    const int half = 1 - (u & 1);                // half1 (more work) first
    const int q0 = tile * 64;
    const int qw = q0 + wid * 16;
    const int l15 = lane & 15, lg = lane >> 4;
    const int swz = (l15 & 7) << 3;
    const int kswz = l15 & 7;

    const __hip_bfloat16* Qbase = Qb + (size_t)bh * 2048 * 64;
    const __hip_bfloat16* Kbase = Kb + (size_t)bh * 2048 * 64;
    const __hip_bfloat16* Vbase = Vt + (size_t)bh * 64 * 2048;

    const bf16x8 aq0 = *(const bf16x8*)(Qbase + (size_t)(qw + l15) * 64 + lg * 8);
    const bf16x8 aq1 = *(const bf16x8*)(Qbase + (size_t)(qw + l15) * 64 + 32 + lg * 8);

    f32x4 o[4] = {};
    float m0 = -1e30f, l0 = 0.f;

    const int nfull = qw >> 6;          // == tile for all waves
    const int nA = tile >> 1;
    const int kt0 = half ? nA : 0;                  // first tile index
    const int ktEnd = half ? (tile + 1) : nA;       // exclusive
    __hip_bfloat16* Pw = &P_lds[wid][0];

    if (ktEnd > kt0) {
        AT_STAGE(0, kt0);
        __syncthreads();                // first tile resident
        int cur = 0;
        for (int tt = kt0; tt < ktEnd; ++tt) {
            if (tt + 1 < ktEnd) AT_STAGE(cur ^ 1, tt + 1);   // prefetch in flight
            if (tt < nfull) {
                FULL_STEP_L(cur);
            } else {
                TAIL_STEP_L(cur);
            }
            __syncthreads();            // drains stage + protects reuse
            cur ^= 1;
        }
    }

    // ---- write partials (un-normalized O + (m,l)) ----
    if (half == 0) {
        const int bq = bh >> 4, hh = bh & 15;
        const int qrow = qw + l15;
        const size_t rowb = ((size_t)(bq * 2048 + qrow)) * 1024 + hh * 64;
#pragma unroll
        for (int dc = 0; dc < 4; ++dc) {
            bf16x4 st;
#pragma unroll
            for (int r = 0; r < 4; ++r)
                st[r] = (short)__bfloat16_as_ushort(__float2bfloat16(o[dc][r]));
            *(bf16x4*)(att + rowb + dc * 16 + lg * 4) = st;
        }
        if (lg == 0) {
            float2 ml;
            ml.x = m0;
            ml.y = l0;
            ((float2*)Pml)[(size_t)bh * 2048 + qrow] = ml;
        }
    } else {
        const size_t prow = (size_t)bh * 2048 + qw + l15;
#pragma unroll
        for (int dc = 0; dc < 4; ++dc) {
            bf16x4 st;
#pragma unroll
            for (int r = 0; r < 4; ++r)
                st[r] = (short)__bfloat16_as_ushort(__float2bfloat16(o[dc][r]));
            *(bf16x4*)(Po + prow * 64 + dc * 16 + lg * 4) = st;
        }
        if (lg == 0) {
            float2 ml;
            ml.x = m0;
            ml.y = l0;
            ((float2*)Pml)[65536 + prow] = ml;
        }
    }
}

// ---------------------------------------------------------------------------
// Merge the two split-K halves: att = (O_A*aA + O_B*aB) / (l_A*aA + l_B*aB).
// O_A lives in att (rewritten in place), O_B in Po. (round-12, verified)
// ---------------------------------------------------------------------------
__global__ __launch_bounds__(256) void k_attn_merge(
    const __hip_bfloat16* __restrict__ Po,
    const float* __restrict__ Pml,
    __hip_bfloat16* __restrict__ att)
{
    const int idx = blockIdx.x * 256 + threadIdx.x;   // 0..524287
    const int row = idx >> 3, seg = idx & 7;
    const float2 mlA = ((const float2*)Pml)[row];
    const float2 mlB = ((const float2*)Pml)[65536 + row];
    const float mf = fmaxf(mlA.x, mlB.x);
    const float aA = exp2fast(mlA.x - mf), aB = exp2fast(mlB.x - mf);
    const float inv = 1.0f / (mlA.y * aA + mlB.y * aB);
    const float fA = aA * inv, fB = aB * inv;
    const int bh = row >> 11, qrow = row & 2047;
    __hip_bfloat16* dst = att + ((size_t)((bh >> 4) * 2048 + qrow) * 1024 + (bh & 15) * 64 + seg * 8);
    const bf16x8 oa = *(const bf16x8*)dst;
    const bf16x8 ob = *(const bf16x8*)(Po + (size_t)row * 64 + seg * 8);
    bf16x8 st;
#pragma unroll
    for (int i = 0; i < 8; ++i)
        st[i] = (short)__bfloat16_as_ushort(f2b(b2f(oa[i]) * fA + b2f(ob[i]) * fB));
    *(bf16x8*)dst = st;
}

// ---------------------------------------------------------------------------
extern "C" void kernel_launch(void* const* d_in, const int* in_sizes, int n_in,
                              void* d_out, int out_size, void* d_ws, size_t ws_size,
                              hipStream_t stream)
{
    const float* x    = (const float*)d_in[0];   // [2,2048,1024]
    const float* Wqkv = (const float*)d_in[1];   // [1024,3072]
    const float* bqkv = (const float*)d_in[2];   // [3072]
    const float* Wo   = (const float*)d_in[3];   // [1024,1024]
    const float* bo   = (const float*)d_in[4];   // [1024]
    float* out = (float*)d_out;                  // [2,2048,1024]

    char* ws = (char*)d_ws;
    const size_t MB = 1024 * 1024;
    __hip_bfloat16* xb    = (__hip_bfloat16*)(ws);            //  8 MB (dead after gemm_qkv)
    __hip_bfloat16* WqkvT = (__hip_bfloat16*)(ws + 8 * MB);   //  6 MB (dead after gemm_qkv)
    __hip_bfloat16* WoT   = (__hip_bfloat16*)(ws + 14 * MB);  //  2 MB (alive till gemm_out)
    __hip_bfloat16* Qb    = (__hip_bfloat16*)(ws + 16 * MB);  //  8 MB
    __hip_bfloat16* Kb    = (__hip_bfloat16*)(ws + 24 * MB);  //  8 MB
    __hip_bfloat16* Vt    = (__hip_bfloat16*)(ws + 32 * MB);  //  8 MB
    __hip_bfloat16* att   = (__hip_bfloat16*)(ws + 40 * MB);  //  8 MB
    __hip_bfloat16* Po    = (__hip_bfloat16*)(ws);            //  8 MB (overlays xb)
    float*          Pml   = (float*)(ws + 8 * MB);            //  1 MB (overlays WqkvT)

    k_prep<<<6144, 256, 0, stream>>>(x, xb, Wqkv, WqkvT, Wo, WoT);

    k_gemm_qkv<<<dim3(24, 32), 256, 0, stream>>>(
        xb, WqkvT, bqkv, 1024, Qb, Kb, Vt);

    k_attn<<<2048, 256, 0, stream>>>(Qb, Kb, Vt, att, Po, Pml);

    k_attn_merge<<<2048, 256, 0, stream>>>(Po, Pml, att);

    k_gemm_out<<<dim3(16, 32), 256, 0, stream>>>(
        att, WoT, bo, 1024, 1024, out);
}

// Round 23
// 115.012 us; speedup vs baseline: 1.0375x; 1.0375x over previous
//
#include <hip/hip_runtime.h>
#include <hip/hip_bf16.h>

typedef __attribute__((ext_vector_type(8))) short bf16x8;
typedef __attribute__((ext_vector_type(4))) short bf16x4;
typedef __attribute__((ext_vector_type(4))) float f32x4;

static __device__ __forceinline__ __hip_bfloat16 f2b(float f) {
    return __float2bfloat16(f);
}
static __device__ __forceinline__ unsigned pack2(float a, float b) {
    unsigned ua = (unsigned)__bfloat16_as_ushort(__float2bfloat16(a));
    unsigned ub = (unsigned)__bfloat16_as_ushort(__float2bfloat16(b));
    return ua | (ub << 16);
}
static __device__ __forceinline__ float exp2fast(float x) {
    return __builtin_amdgcn_exp2f(x);
}

#define QSCALE 0.1803368801111f   // 0.125 * log2(e)

// ---------------------------------------------------------------------------
// Fused prep: blocks [0,2048) convert x f32->bf16; [2048,5120) transpose
// Wqkv -> WqkvT bf16; [5120,6144) transpose Wo -> WoT bf16.
// ---------------------------------------------------------------------------
__global__ __launch_bounds__(256) void k_prep(
    const float* __restrict__ x, __hip_bfloat16* __restrict__ xb,
    const float* __restrict__ Wqkv, __hip_bfloat16* __restrict__ WqkvT,
    const float* __restrict__ Wo, __hip_bfloat16* __restrict__ WoT)
{
    const int bx = blockIdx.x;
    if (bx < 2048) {
        int i = bx * 256 + threadIdx.x;
        const int stride = 2048 * 256;
        for (; i < 1048576; i += stride) {
            float4 v = reinterpret_cast<const float4*>(x)[i];
            __hip_bfloat16* o = xb + 4 * (size_t)i;
            o[0] = f2b(v.x); o[1] = f2b(v.y); o[2] = f2b(v.z); o[3] = f2b(v.w);
        }
        return;
    }
    __shared__ float tile[32][33];
    const float* in;
    __hip_bfloat16* outp;
    int R, Cn, c0, r0;
    if (bx < 5120) {
        const int b = bx - 2048;
        in = Wqkv; outp = WqkvT; R = 1024; Cn = 3072;
        c0 = (b % 96) * 32; r0 = (b / 96) * 32;
    } else {
        const int b = bx - 5120;
        in = Wo; outp = WoT; R = 1024; Cn = 1024;
        c0 = (b & 31) * 32; r0 = (b >> 5) * 32;
    }
    const int tx = threadIdx.x & 31, ty = threadIdx.x >> 5;
#pragma unroll
    for (int i = 0; i < 32; i += 8)
        tile[ty + i][tx] = in[(size_t)(r0 + ty + i) * Cn + c0 + tx];
    __syncthreads();
#pragma unroll
    for (int i = 0; i < 32; i += 8)
        outp[(size_t)(c0 + ty + i) * R + r0 + tx] = f2b(tile[tx][ty + i]);
}

// ---------------------------------------------------------------------------
// GEMM1 qkv: 128x128 tile, BK=32, TWO-buffer dbuf LDS with __syncthreads
// (round-8 version: verified clean in 5 benches; no raw barriers).
// ---------------------------------------------------------------------------
#define QK_STAGE(buf, kt)                                                       \
    {                                                                           \
        const int k0_ = (kt) << 5;                                              \
        _Pragma("unroll")                                                       \
        for (int i = 0; i < 2; ++i) {                                           \
            const int idx = i * 256 + tid;                                      \
            const int r_ = idx >> 2;                                            \
            const int j_ = idx & 3;                                             \
            const int js_ = j_ ^ ((r_ >> 1) & 3);                               \
            __builtin_amdgcn_global_load_lds(                                   \
                (const __attribute__((address_space(1))) void*)(A + (size_t)(m0 + r_) * K + k0_ + js_ * 8), \
                (__attribute__((address_space(3))) void*)(&As[buf][r_][j_ * 8]), 16, 0, 0); \
        }                                                                       \
        _Pragma("unroll")                                                       \
        for (int i = 0; i < 2; ++i) {                                           \
            const int idx = i * 256 + tid;                                      \
            const int r_ = idx >> 2;                                            \
            const int j_ = idx & 3;                                             \
            const int js_ = j_ ^ ((r_ >> 1) & 3);                               \
            __builtin_amdgcn_global_load_lds(                                   \
                (const __attribute__((address_space(1))) void*)(Bt + (size_t)(n0 + r_) * K + k0_ + js_ * 8), \
                (__attribute__((address_space(3))) void*)(&Bs[buf][r_][j_ * 8]), 16, 0, 0); \
        }                                                                       \
    }

__global__ __launch_bounds__(256, 3) void k_gemm_qkv(
    const __hip_bfloat16* __restrict__ A,
    const __hip_bfloat16* __restrict__ Bt,
    const float* __restrict__ bias,
    int K,
    __hip_bfloat16* __restrict__ Qb,
    __hip_bfloat16* __restrict__ Kb,
    __hip_bfloat16* __restrict__ Vt)
{
    __shared__ __hip_bfloat16 As[2][128][32];
    __shared__ __hip_bfloat16 Bs[2][128][32];

    const int tid = threadIdx.x;
    const int lane = tid & 63;
    const int wid = tid >> 6;
    const int wm = wid >> 1, wn = wid & 1;
    const int m0 = blockIdx.y * 128, n0 = blockIdx.x * 128;
    const int l15 = lane & 15, lg = lane >> 4;
    const int rchunk = (lg ^ ((l15 >> 1) & 3)) * 8;   // swizzled read chunk

    f32x4 acc[4][4] = {};
    const int nt = K >> 5;   // 32

    QK_STAGE(0, 0);
    __syncthreads();
    int cur = 0;
    for (int t = 0; t < nt; ++t) {
        if (t + 1 < nt) QK_STAGE(cur ^ 1, t + 1);
        bf16x8 a[4], bb[4];
#pragma unroll
        for (int m = 0; m < 4; ++m)
            a[m] = *(const bf16x8*)&As[cur][wm * 64 + m * 16 + l15][rchunk];
#pragma unroll
        for (int n = 0; n < 4; ++n)
            bb[n] = *(const bf16x8*)&Bs[cur][wn * 64 + n * 16 + l15][rchunk];
        __builtin_amdgcn_s_setprio(1);
#pragma unroll
        for (int m = 0; m < 4; ++m)
#pragma unroll
            for (int n = 0; n < 4; ++n)
                acc[m][n] = __builtin_amdgcn_mfma_f32_16x16x32_bf16(a[m], bb[n], acc[m][n], 0, 0, 0);
        __builtin_amdgcn_s_setprio(0);
        __syncthreads();
        cur ^= 1;
    }

#pragma unroll
    for (int m = 0; m < 4; ++m) {
        const int row = m0 + wm * 64 + m * 16 + lg * 4;
#pragma unroll
        for (int n = 0; n < 4; ++n) {
            const int col = n0 + wn * 64 + n * 16 + l15;
            const float bv = bias[col];
#pragma unroll
            for (int r = 0; r < 4; ++r) {
                const float val = acc[m][n][r] + bv;
                const int rr = row + r;
                const int sec = col >> 10, cw = col & 1023;
                const int hh = cw >> 6, d = cw & 63;
                const int bq = rr >> 11, tt = rr & 2047;
                const int bh = bq * 16 + hh;
                if (sec == 0)
                    Qb[((size_t)bh * 2048 + tt) * 64 + d] = f2b(val * QSCALE);
                else if (sec == 1)
                    Kb[((size_t)bh * 2048 + tt) * 64 + d] = f2b(val);
                else
                    Vt[((size_t)bh * 64 + d) * 2048 + tt] = f2b(val);
            }
        }
    }
}

// ---------------------------------------------------------------------------
// GEMM out: 128x64 tile, BK=32, TWO-buffer dbuf with __syncthreads.
// (round-8 version: verified clean in 5 benches.)
// ---------------------------------------------------------------------------
#define OUT_STAGE(buf, kt)                                                      \
    {                                                                           \
        const int k0_ = (kt) << 5;                                              \
        _Pragma("unroll")                                                       \
        for (int i = 0; i < 2; ++i) {                                           \
            const int idx = i * 256 + tid;                                      \
            const int r_ = idx >> 2;                                            \
            const int j_ = idx & 3;                                             \
            const int js_ = j_ ^ ((r_ >> 1) & 3);                               \
            __builtin_amdgcn_global_load_lds(                                   \
                (const __attribute__((address_space(1))) void*)(A + (size_t)(m0 + r_) * K + k0_ + js_ * 8), \
                (__attribute__((address_space(3))) void*)(&As[buf][r_][j_ * 8]), 16, 0, 0); \
        }                                                                       \
        {                                                                       \
            const int r_ = tid >> 2;                                            \
            const int j_ = tid & 3;                                             \
            const int js_ = j_ ^ ((r_ >> 1) & 3);                               \
            __builtin_amdgcn_global_load_lds(                                   \
                (const __attribute__((address_space(1))) void*)(Bt + (size_t)(n0 + r_) * K + k0_ + js_ * 8), \
                (__attribute__((address_space(3))) void*)(&Bs[buf][r_][j_ * 8]), 16, 0, 0); \
        }                                                                       \
    }

__global__ __launch_bounds__(256, 4) void k_gemm_out(
    const __hip_bfloat16* __restrict__ A,
    const __hip_bfloat16* __restrict__ Bt,
    const float* __restrict__ bias,
    int K, int Nn,
    float* __restrict__ outf)
{
    __shared__ __hip_bfloat16 As[2][128][32];
    __shared__ __hip_bfloat16 Bs[2][64][32];

    const int tid = threadIdx.x;
    const int lane = tid & 63;
    const int wid = tid >> 6;
    const int wm = wid >> 1, wn = wid & 1;
    const int m0 = blockIdx.y * 128, n0 = blockIdx.x * 64;
    const int l15 = lane & 15, lg = lane >> 4;
    const int rchunk = (lg ^ ((l15 >> 1) & 3)) * 8;

    f32x4 acc[4][2] = {};
    const int nt = K >> 5;

    OUT_STAGE(0, 0);
    __syncthreads();
    int cur = 0;
    for (int t = 0; t < nt; ++t) {
        if (t + 1 < nt) OUT_STAGE(cur ^ 1, t + 1);
        bf16x8 a[4], bb[2];
#pragma unroll
        for (int m = 0; m < 4; ++m)
            a[m] = *(const bf16x8*)&As[cur][wm * 64 + m * 16 + l15][rchunk];
#pragma unroll
        for (int n = 0; n < 2; ++n)
            bb[n] = *(const bf16x8*)&Bs[cur][wn * 32 + n * 16 + l15][rchunk];
        __builtin_amdgcn_s_setprio(1);
#pragma unroll
        for (int m = 0; m < 4; ++m)
#pragma unroll
            for (int n = 0; n < 2; ++n)
                acc[m][n] = __builtin_amdgcn_mfma_f32_16x16x32_bf16(a[m], bb[n], acc[m][n], 0, 0, 0);
        __builtin_amdgcn_s_setprio(0);
        __syncthreads();
        cur ^= 1;
    }

#pragma unroll
    for (int m = 0; m < 4; ++m) {
        const int row = m0 + wm * 64 + m * 16 + lg * 4;
#pragma unroll
        for (int n = 0; n < 2; ++n) {
            const int col = n0 + wn * 32 + n * 16 + l15;
            const float bv = bias[col];
#pragma unroll
            for (int r = 0; r < 4; ++r)
                outf[(size_t)(row + r) * Nn + col] = acc[m][n][r] + bv;
        }
    }
}

// ---------------------------------------------------------------------------
// Causal flash attention v15 — block-shared K/V staging, 16 q-rows/wave,
// 1024 blocks x 4 waves over 64-row q-tiles. LDS 40 KB -> 4 blocks/CU
// (160 KB exact) = 16 waves/CU. VGPR 56, zero spill. All-__syncthreads.
// (round-20 version, verified 45.9 us)
// ---------------------------------------------------------------------------
#define DEFER_THR 4.0f

#define AT_STAGE(buf, tt)                                                       \
    {                                                                           \
        const int ks_ = (tt) << 6;                                              \
        _Pragma("unroll")                                                       \
        for (int i = 0; i < 2; ++i) {                                           \
            const int idx = i * 256 + tid;                                      \
            const int r_ = idx >> 3;                                            \
            const int j_ = idx & 7;                                             \
            const int js_ = j_ ^ (r_ & 7);                                      \
            __builtin_amdgcn_global_load_lds(                                   \
                (const __attribute__((address_space(1))) void*)(Kbase + (size_t)(ks_ + r_) * 64 + js_ * 8), \
                (__attribute__((address_space(3))) void*)(&Ks[buf][r_][j_ * 8]), 16, 0, 0); \
        }                                                                       \
        _Pragma("unroll")                                                       \
        for (int i = 0; i < 2; ++i) {                                           \
            const int idx = i * 256 + tid;                                      \
            const int r_ = idx >> 3;                                            \
            const int j_ = idx & 7;                                             \
            const int js_ = j_ ^ (r_ & 7);                                      \
            __builtin_amdgcn_global_load_lds(                                   \
                (const __attribute__((address_space(1))) void*)(Vbase + (size_t)r_ * 2048 + ks_ + js_ * 8), \
                (__attribute__((address_space(3))) void*)(&Vs[buf][r_][j_ * 8]), 16, 0, 0); \
        }                                                                       \
    }

#define FULL_STEP_L(BUF)                                                        \
    {                                                                           \
        bf16x8 bk0[4], bk1[4];                                                  \
        _Pragma("unroll")                                                       \
        for (int kf = 0; kf < 4; ++kf) {                                        \
            bk0[kf] = *(const bf16x8*)&Ks[BUF][kf * 16 + l15][(lg ^ kswz) * 8]; \
            bk1[kf] = *(const bf16x8*)&Ks[BUF][kf * 16 + l15][((4 + lg) ^ kswz) * 8]; \
        }                                                                       \
        f32x4 s[4] = {};                                                        \
        __builtin_amdgcn_s_setprio(1);                                          \
        _Pragma("unroll")                                                       \
        for (int kf = 0; kf < 4; ++kf) {                                        \
            s[kf] = __builtin_amdgcn_mfma_f32_16x16x32_bf16(bk0[kf], aq0, s[kf], 0, 0, 0); \
            s[kf] = __builtin_amdgcn_mfma_f32_16x16x32_bf16(bk1[kf], aq1, s[kf], 0, 0, 0); \
        }                                                                       \
        __builtin_amdgcn_s_setprio(0);                                          \
        float px = fmaxf(fmaxf(fmaxf(s[0][0], s[0][1]), fmaxf(s[0][2], s[0][3])), \
                         fmaxf(fmaxf(s[1][0], s[1][1]), fmaxf(s[1][2], s[1][3]))); \
        px = fmaxf(px, fmaxf(fmaxf(fmaxf(s[2][0], s[2][1]), fmaxf(s[2][2], s[2][3])), \
                             fmaxf(fmaxf(s[3][0], s[3][1]), fmaxf(s[3][2], s[3][3])))); \
        px = fmaxf(px, __shfl_xor(px, 16));                                     \
        px = fmaxf(px, __shfl_xor(px, 32));                                     \
        if (__any(px > m0 + DEFER_THR)) {                                       \
            const float mn_ = fmaxf(m0, px);                                    \
            const float al_ = exp2fast(m0 - mn_);                               \
            m0 = mn_; l0 *= al_;                                                \
            _Pragma("unroll")                                                   \
            for (int dc = 0; dc < 4; ++dc)                                      \
                _Pragma("unroll")                                               \
                for (int r = 0; r < 4; ++r) o[dc][r] *= al_;                    \
        }                                                                       \
        float rs_ = 0.f;                                                        \
        _Pragma("unroll")                                                       \
        for (int kf = 0; kf < 4; ++kf) {                                        \
            _Pragma("unroll")                                                   \
            for (int r = 0; r < 4; ++r) {                                       \
                s[kf][r] = exp2fast(s[kf][r] - m0);                             \
                rs_ += s[kf][r];                                                \
            }                                                                   \
            uint2 w_;                                                           \
            w_.x = pack2(s[kf][0], s[kf][1]);                                   \
            w_.y = pack2(s[kf][2], s[kf][3]);                                   \
            *(uint2*)&Pw[l15 * 64 + ((kf * 16 + lg * 4) ^ swz)] = w_;           \
        }                                                                       \
        rs_ += __shfl_xor(rs_, 16);                                             \
        rs_ += __shfl_xor(rs_, 32);                                             \
        l0 += rs_;                                                              \
        _Pragma("unroll")                                                       \
        for (int c2 = 0; c2 < 2; ++c2) {                                        \
            bf16x8 bv[4];                                                       \
            _Pragma("unroll")                                                   \
            for (int dc = 0; dc < 4; ++dc)                                      \
                bv[dc] = *(const bf16x8*)&Vs[BUF][dc * 16 + l15][(((c2 << 2) | lg) ^ kswz) * 8]; \
            const bf16x8 pb = *(const bf16x8*)&Pw[l15 * 64 + ((c2 * 32 + lg * 8) ^ swz)]; \
            __builtin_amdgcn_s_setprio(1);                                      \
            _Pragma("unroll")                                                   \
            for (int dc = 0; dc < 4; ++dc)                                      \
                o[dc] = __builtin_amdgcn_mfma_f32_16x16x32_bf16(bv[dc], pb, o[dc], 0, 0, 0); \
            __builtin_amdgcn_s_setprio(0);                                      \
        }                                                                       \
    }

#define TAIL_STEP_L(BUF)                                                        \
    {                                                                           \
        const int ks_ = nfull * 64;                                             \
        const int qv = qw + l15;                                                \
        bf16x8 bk0[4], bk1[4];                                                  \
        _Pragma("unroll")                                                       \
        for (int kf = 0; kf < 4; ++kf) {                                        \
            bk0[kf] = *(const bf16x8*)&Ks[BUF][kf * 16 + l15][(lg ^ kswz) * 8]; \
            bk1[kf] = *(const bf16x8*)&Ks[BUF][kf * 16 + l15][((4 + lg) ^ kswz) * 8]; \
        }                                                                       \
        f32x4 s[4] = {};                                                        \
        _Pragma("unroll")                                                       \
        for (int kf = 0; kf < 4; ++kf) {                                        \
            if (ks_ + kf * 16 <= qw + 15) {                                     \
                s[kf] = __builtin_amdgcn_mfma_f32_16x16x32_bf16(bk0[kf], aq0, s[kf], 0, 0, 0); \
                s[kf] = __builtin_amdgcn_mfma_f32_16x16x32_bf16(bk1[kf], aq1, s[kf], 0, 0, 0); \
            }                                                                   \
        }                                                                       \
        const int kb = ks_ + lg * 4;                                            \
        _Pragma("unroll")                                                       \
        for (int kf = 0; kf < 4; ++kf)                                          \
            _Pragma("unroll")                                                   \
            for (int r = 0; r < 4; ++r)                                         \
                s[kf][r] = (kb + kf * 16 + r <= qv) ? s[kf][r] : -1e30f;        \
        float mx = fmaxf(fmaxf(fmaxf(s[0][0], s[0][1]), fmaxf(s[0][2], s[0][3])), \
                         fmaxf(fmaxf(s[1][0], s[1][1]), fmaxf(s[1][2], s[1][3]))); \
        mx = fmaxf(mx, fmaxf(fmaxf(fmaxf(s[2][0], s[2][1]), fmaxf(s[2][2], s[2][3])), \
                             fmaxf(fmaxf(s[3][0], s[3][1]), fmaxf(s[3][2], s[3][3])))); \
        mx = fmaxf(mx, __shfl_xor(mx, 16));                                     \
        mx = fmaxf(mx, __shfl_xor(mx, 32));                                     \
        const float mnew = fmaxf(m0, mx);                                       \
        const float al_ = exp2fast(m0 - mnew);                                  \
        m0 = mnew;                                                              \
        float rs_ = 0.f;                                                        \
        _Pragma("unroll")                                                       \
        for (int kf = 0; kf < 4; ++kf)                                          \
            _Pragma("unroll")                                                   \
            for (int r = 0; r < 4; ++r) {                                       \
                s[kf][r] = exp2fast(s[kf][r] - mnew);                           \
                rs_ += s[kf][r];                                                \
            }                                                                   \
        rs_ += __shfl_xor(rs_, 16);                                             \
        rs_ += __shfl_xor(rs_, 32);                                             \
        l0 = l0 * al_ + rs_;                                                    \
        _Pragma("unroll")                                                       \
        for (int dc = 0; dc < 4; ++dc)                                          \
            _Pragma("unroll")                                                   \
            for (int r = 0; r < 4; ++r) o[dc][r] *= al_;                        \
        _Pragma("unroll")                                                       \
        for (int kf = 0; kf < 4; ++kf) {                                        \
            uint2 w_;                                                           \
            w_.x = pack2(s[kf][0], s[kf][1]);                                   \
            w_.y = pack2(s[kf][2], s[kf][3]);                                   \
            *(uint2*)&Pw[l15 * 64 + ((kf * 16 + lg * 4) ^ swz)] = w_;           \
        }                                                                       \
        _Pragma("unroll")                                                       \
        for (int c2 = 0; c2 < 2; ++c2) {                                        \
            if (ks_ + c2 * 32 <= qw + 15) {                                     \
                bf16x8 bv[4];                                                   \
                _Pragma("unroll")                                               \
                for (int dc = 0; dc < 4; ++dc)                                  \
                    bv[dc] = *(const bf16x8*)&Vs[BUF][dc * 16 + l15][(((c2 << 2) | lg) ^ kswz) * 8]; \
                const bf16x8 pb = *(const bf16x8*)&Pw[l15 * 64 + ((c2 * 32 + lg * 8) ^ swz)]; \
                _Pragma("unroll")                                               \
                for (int dc = 0; dc < 4; ++dc)                                  \
                    o[dc] = __builtin_amdgcn_mfma_f32_16x16x32_bf16(bv[dc], pb, o[dc], 0, 0, 0); \
            }                                                                   \
        }                                                                       \
    }

__global__ __launch_bounds__(256, 4) void k_attn(
    const __hip_bfloat16* __restrict__ Qb,
    const __hip_bfloat16* __restrict__ Kb,
    const __hip_bfloat16* __restrict__ Vt,
    __hip_bfloat16* __restrict__ att)
{
    __shared__ __hip_bfloat16 Ks[2][64][64];          // 16 KB
    __shared__ __hip_bfloat16 Vs[2][64][64];          // 16 KB (row=d, col=key)
    __shared__ __hip_bfloat16 P_lds[4][16 * 64];      //  8 KB
    const int tid = threadIdx.x, lane = tid & 63, wid = tid >> 6;
    const int lid = blockIdx.x;                  // 0..1023
    const int xcd = lid & 7, j = lid >> 3;       // j 0..127
    const int bh = xcd * 4 + (j & 3);            // 4 heads per XCD
    const int v = j >> 2;                        // 0..31
    // complementary tile map: per-CU slot-set sums constant
    const int tile = (v < 8) ? (31 - v) : ((v < 16) ? (v - 8) : ((v < 24) ? (39 - v) : (v - 16)));
    const int q0 = tile * 64;
    const int qw = q0 + wid * 16;
    const int l15 = lane & 15, lg = lane >> 4;
    const int swz = (l15 & 7) << 3;
    const int kswz = l15 & 7;

    const __hip_bfloat16* Qbase = Qb + (size_t)bh * 2048 * 64;
    const __hip_bfloat16* Kbase = Kb + (size_t)bh * 2048 * 64;
    const __hip_bfloat16* Vbase = Vt + (size_t)bh * 64 * 2048;

    const bf16x8 aq0 = *(const bf16x8*)(Qbase + (size_t)(qw + l15) * 64 + lg * 8);
    const bf16x8 aq1 = *(const bf16x8*)(Qbase + (size_t)(qw + l15) * 64 + 32 + lg * 8);

    f32x4 o[4] = {};
    float m0 = -1e30f, l0 = 0.f;

    const int nfull = qw >> 6;          // == tile for all waves (wid*16 < 64)
    const int NT = tile + 1;            // tiles this block touches
    __hip_bfloat16* Pw = &P_lds[wid][0];

    AT_STAGE(0, 0);
    __syncthreads();                    // tile 0 resident

    int cur = 0;
    for (int tt = 0; tt < NT; ++tt) {
        if (tt + 1 < NT) AT_STAGE(cur ^ 1, tt + 1);   // prefetch in flight
        if (tt < nfull) {
            FULL_STEP_L(cur);
        } else {
            TAIL_STEP_L(cur);
        }
        __syncthreads();                // drains stage + protects reuse
        cur ^= 1;
    }

    const int bq = bh >> 4, hh = bh & 15;
    const float inv = 1.0f / l0;
    const size_t rowb = ((size_t)(bq * 2048 + qw + l15)) * 1024 + hh * 64;
#pragma unroll
    for (int dc = 0; dc < 4; ++dc) {
        bf16x4 st;
#pragma unroll
        for (int r = 0; r < 4; ++r)
            st[r] = (short)__bfloat16_as_ushort(__float2bfloat16(o[dc][r] * inv));
        *(bf16x4*)(att + rowb + dc * 16 + lg * 4) = st;
    }
}

// ---------------------------------------------------------------------------
extern "C" void kernel_launch(void* const* d_in, const int* in_sizes, int n_in,
                              void* d_out, int out_size, void* d_ws, size_t ws_size,
                              hipStream_t stream)
{
    const float* x    = (const float*)d_in[0];   // [2,2048,1024]
    const float* Wqkv = (const float*)d_in[1];   // [1024,3072]
    const float* bqkv = (const float*)d_in[2];   // [3072]
    const float* Wo   = (const float*)d_in[3];   // [1024,1024]
    const float* bo   = (const float*)d_in[4];   // [1024]
    float* out = (float*)d_out;                  // [2,2048,1024]

    char* ws = (char*)d_ws;
    const size_t MB = 1024 * 1024;
    __hip_bfloat16* xb    = (__hip_bfloat16*)(ws);            //  8 MB
    __hip_bfloat16* WqkvT = (__hip_bfloat16*)(ws + 8 * MB);   //  6 MB
    __hip_bfloat16* WoT   = (__hip_bfloat16*)(ws + 14 * MB);  //  2 MB
    __hip_bfloat16* Qb    = (__hip_bfloat16*)(ws + 16 * MB);  //  8 MB
    __hip_bfloat16* Kb    = (__hip_bfloat16*)(ws + 24 * MB);  //  8 MB
    __hip_bfloat16* Vt    = (__hip_bfloat16*)(ws + 32 * MB);  //  8 MB
    __hip_bfloat16* att   = (__hip_bfloat16*)(ws + 40 * MB);  //  8 MB

    k_prep<<<6144, 256, 0, stream>>>(x, xb, Wqkv, WqkvT, Wo, WoT);

    k_gemm_qkv<<<dim3(24, 32), 256, 0, stream>>>(
        xb, WqkvT, bqkv, 1024, Qb, Kb, Vt);

    k_attn<<<1024, 256, 0, stream>>>(Qb, Kb, Vt, att);

    k_gemm_out<<<dim3(16, 32), 256, 0, stream>>>(
        att, WoT, bo, 1024, 1024, out);
}